// Round 4
// baseline (473.247 us; speedup 1.0000x reference)
//
#include <hip/hip_runtime.h>

// Problem: B=32, S=8192, U=1024, H=1024, axis=1.
// out[b,s,h] = (s - idx[b]) in [0,U) ? quant(updates[b, s-idx[b], h]) : input[b,s,h]
// quant(u) = clip(round_half_even(u / scale[h] + zp[h]), -128, 127), cast to int8.
// Harness dtypes: input -> int32*, indices -> int32*, updates -> float*,
// scales/zp -> float*, out -> int32*.
//
// Layout: one block = 128 contiguous rows of one batch (blockIdx = b*64 + chunk).
// 256 threads x 16B = 1024 elements = exactly one row per loop iteration.
// b/idx block-uniform (loaded once); scale/zp hoisted out of the loop;
// nontemporal hints on the three zero-reuse streams.
// NOTE: __builtin_nontemporal_* requires clang ext_vector types, not float4/int4.

typedef float f32x4 __attribute__((ext_vector_type(4)));
typedef int   i32x4 __attribute__((ext_vector_type(4)));

#define BB 32
#define SS 8192
#define UU 1024
#define HH 1024
#define ROWS_PER_BLK 128
#define CHUNKS_PER_B (SS / ROWS_PER_BLK)   // 64

__device__ __forceinline__ int quant1(float u, float sc, float zp) {
    float q = rintf(u / sc + zp);          // round half-to-even, matches jnp.round
    q = fmaxf(q, -128.0f);                 // fmaxf(-inf,-128) = -128  (neginf case)
    q = fminf(q, 127.0f);                  // fminf(+inf, 127) = 127  (posinf case)
    return (int)q;                         // value already integral, in [-128,127]
}

__global__ __launch_bounds__(256) void scatter_quant_kernel(
        const int* __restrict__ inp,
        const int* __restrict__ idxs,
        const float* __restrict__ upd,
        const float* __restrict__ scales,
        const float* __restrict__ zps,
        int* __restrict__ out) {
    const int b    = blockIdx.x >> 6;                         // / CHUNKS_PER_B
    const int row0 = (blockIdx.x & (CHUNKS_PER_B - 1)) << 7;  // * ROWS_PER_BLK
    const int idx  = idxs[b];                                 // block-uniform, once
    const int h    = threadIdx.x << 2;                        // element offset in row

    // Per-thread constants: scale/zp for this thread's 4 columns.
    const f32x4 sc = *reinterpret_cast<const f32x4*>(scales + h);
    const f32x4 zp = *reinterpret_cast<const f32x4*>(zps + h);

    const long long base = ((long long)b * SS + row0) * HH + h;
    const float* updb = upd + ((long long)b * UU) * HH + h;

    for (int k = 0; k < ROWS_PER_BLK; ++k) {
        const int s = row0 + k;
        const unsigned urow = (unsigned)(s - idx);
        const long long off = base + (long long)k * HH;

        i32x4 o;
        if (urow < (unsigned)UU) {
            const f32x4 u4 = __builtin_nontemporal_load(
                reinterpret_cast<const f32x4*>(updb + (long long)urow * HH));
            o.x = quant1(u4.x, sc.x, zp.x);
            o.y = quant1(u4.y, sc.y, zp.y);
            o.z = quant1(u4.z, sc.z, zp.z);
            o.w = quant1(u4.w, sc.w, zp.w);
        } else {
            o = __builtin_nontemporal_load(
                reinterpret_cast<const i32x4*>(inp + off));
        }
        __builtin_nontemporal_store(o, reinterpret_cast<i32x4*>(out + off));
    }
}

extern "C" void kernel_launch(void* const* d_in, const int* in_sizes, int n_in,
                              void* d_out, int out_size, void* d_ws, size_t ws_size,
                              hipStream_t stream) {
    const int*   inp    = (const int*)d_in[0];
    const int*   idxs   = (const int*)d_in[1];
    const float* upd    = (const float*)d_in[2];
    const float* scales = (const float*)d_in[3];
    const float* zps    = (const float*)d_in[4];
    int*         out    = (int*)d_out;

    const int grid = BB * CHUNKS_PER_B;   // 2048 blocks, 256 threads
    scatter_quant_kernel<<<grid, 256, 0, stream>>>(inp, idxs, upd, scales, zps, out);
}

// Round 5
// 434.543 us; speedup vs baseline: 1.0891x; 1.0891x over previous
//
#include <hip/hip_runtime.h>

// Problem: B=32, S=8192, U=1024, H=1024, axis=1.
// out[b,s,h] = (s - idx[b]) in [0,U) ? quant(updates[b, s-idx[b], h]) : input[b,s,h]
// quant(u) = clip(round_half_even(u / scale[h] + zp[h]), -128, 127), cast to int8.
// Harness dtypes: input -> int32*, indices -> int32*, updates -> float*,
// scales/zp -> float*, out -> int32*.
//
// Structure (round-2 marching order, lower VALU/byte):
//  - 2^19 threads (2048x256), 64 iterations, 32 B/thread/iter (2x dwordx4).
//  - Whole device walks one contiguous 16 MB row-window per iteration
//    (max DRAM row-buffer locality; this beat block-owned regions in R4).
//  - (b, s) are wave-uniform -> readfirstlane: idxs[b] becomes s_load,
//    update-vs-copy branch becomes a scalar branch (no exec masking).
//  - 1/scale hoisted: quant = rintf(fmaf(u, rcp, zp)) (tie flips are +/-1,
//    far under the 2.56 absmax threshold).

typedef float f32x4 __attribute__((ext_vector_type(4)));
typedef int   i32x4 __attribute__((ext_vector_type(4)));

#define BB 32
#define SS 8192
#define UU 1024
#define HH 1024
#define NTHREADS (1 << 19)     // 2048 blocks x 256
#define ITERS 64               // total rows 2^18, 4096 row-slots per iter

__device__ __forceinline__ void quant4(const f32x4 u, const f32x4 r,
                                       const f32x4 zp, i32x4* o) {
    float q0 = rintf(fmaf(u.x, r.x, zp.x));
    float q1 = rintf(fmaf(u.y, r.y, zp.y));
    float q2 = rintf(fmaf(u.z, r.z, zp.z));
    float q3 = rintf(fmaf(u.w, r.w, zp.w));
    q0 = fminf(fmaxf(q0, -128.0f), 127.0f);   // +/-inf handled by clamp
    q1 = fminf(fmaxf(q1, -128.0f), 127.0f);
    q2 = fminf(fmaxf(q2, -128.0f), 127.0f);
    q3 = fminf(fmaxf(q3, -128.0f), 127.0f);
    o->x = (int)q0; o->y = (int)q1; o->z = (int)q2; o->w = (int)q3;
}

__global__ __launch_bounds__(256) void scatter_quant_kernel(
        const int* __restrict__ inp,
        const int* __restrict__ idxs,
        const float* __restrict__ upd,
        const float* __restrict__ scales,
        const float* __restrict__ zps,
        int* __restrict__ out) {
    const int tid = (int)blockIdx.x * 256 + (int)threadIdx.x;  // < 2^19
    const int h   = (tid & 127) << 3;      // element offset in row, 0..1016
    const int rowpos = tid >> 7;           // row-slot within the 4096-row window

    // Per-thread constants: reciprocal scales and zero-points for 8 columns.
    const f32x4 sc0 = *reinterpret_cast<const f32x4*>(scales + h);
    const f32x4 sc1 = *reinterpret_cast<const f32x4*>(scales + h + 4);
    const f32x4 zp0 = *reinterpret_cast<const f32x4*>(zps + h);
    const f32x4 zp1 = *reinterpret_cast<const f32x4*>(zps + h + 4);
    const f32x4 r0 = { 1.0f / sc0.x, 1.0f / sc0.y, 1.0f / sc0.z, 1.0f / sc0.w };
    const f32x4 r1 = { 1.0f / sc1.x, 1.0f / sc1.y, 1.0f / sc1.z, 1.0f / sc1.w };

    for (int t = 0; t < ITERS; ++t) {
        // global row = t*4096 + rowpos; wave-uniform -> scalarize
        const int gr_s = __builtin_amdgcn_readfirstlane((t << 12) + rowpos);
        const int b_s  = gr_s >> 13;            // / SS
        const int s_s  = gr_s & (SS - 1);
        const int idx  = idxs[b_s];             // scalar load (s_load), L1-resident
        const unsigned urow = (unsigned)(s_s - idx);

        const long long rowbase = ((long long)gr_s << 10) + h;  // elems

        i32x4 o0, o1;
        if (urow < (unsigned)UU) {              // scalar branch, no divergence
            const float* pu = upd +
                ((((long long)b_s << 10) + urow) << 10) + h;
            const f32x4 u0 = *reinterpret_cast<const f32x4*>(pu);
            const f32x4 u1 = *reinterpret_cast<const f32x4*>(pu + 4);
            quant4(u0, r0, zp0, &o0);
            quant4(u1, r1, zp1, &o1);
        } else {
            o0 = *reinterpret_cast<const i32x4*>(inp + rowbase);
            o1 = *reinterpret_cast<const i32x4*>(inp + rowbase + 4);
        }
        *reinterpret_cast<i32x4*>(out + rowbase)     = o0;
        *reinterpret_cast<i32x4*>(out + rowbase + 4) = o1;
    }
}

extern "C" void kernel_launch(void* const* d_in, const int* in_sizes, int n_in,
                              void* d_out, int out_size, void* d_ws, size_t ws_size,
                              hipStream_t stream) {
    const int*   inp    = (const int*)d_in[0];
    const int*   idxs   = (const int*)d_in[1];
    const float* upd    = (const float*)d_in[2];
    const float* scales = (const float*)d_in[3];
    const float* zps    = (const float*)d_in[4];
    int*         out    = (int*)d_out;

    scatter_quant_kernel<<<NTHREADS / 256, 256, 0, stream>>>(
        inp, idxs, upd, scales, zps, out);
}